// Round 2
// baseline (727.628 us; speedup 1.0000x reference)
//
#include <hip/hip_runtime.h>
#include <hip/hip_bf16.h>

typedef __attribute__((ext_vector_type(8))) __bf16 bf16x8;
typedef __attribute__((ext_vector_type(4))) __bf16 bf16x4;
typedef __attribute__((ext_vector_type(4))) float f32x4;
typedef __attribute__((ext_vector_type(2))) float f32x2;

#define MFMA(a, b, c) __builtin_amdgcn_mfma_f32_16x16x32_bf16((a), (b), (c), 0, 0, 0)

// load 8 consecutive f32, convert to bf16x8 fragment
__device__ __forceinline__ bf16x8 cvt8(const float* __restrict__ p) {
    const f32x4 a = *(const f32x4*)(p);
    const f32x4 b = *(const f32x4*)(p + 4);
    bf16x8 r;
    r[0] = (__bf16)a[0]; r[1] = (__bf16)a[1]; r[2] = (__bf16)a[2]; r[3] = (__bf16)a[3];
    r[4] = (__bf16)b[0]; r[5] = (__bf16)b[1]; r[6] = (__bf16)b[2]; r[7] = (__bf16)b[3];
    return r;
}

// HW fp32 atomic add (no CAS loop). Packed v2f32 when the builtin exists.
__device__ __forceinline__ void atom2(float* p, float a, float b) {
#if __has_builtin(__builtin_amdgcn_global_atomic_fadd_v2f32)
    typedef f32x2 __attribute__((address_space(1)))* gp2;
    f32x2 v = {a, b};
    __builtin_amdgcn_global_atomic_fadd_v2f32((gp2)(unsigned long long)p, v);
#else
    unsafeAtomicAdd(p, a);
    unsafeAtomicAdd(p + 1, b);
#endif
}

// ---------------------------------------------------------------------------
// Kernel 1 (transposed): y1 = x @ W1a[0:128,:] + b1a ; y2 = x @ W2a[0:128,:] + b2a
// D^T form: lane l15 owns one node row, holds 4 consecutive out-cols per acc reg.
// ---------------------------------------------------------------------------
__global__ __launch_bounds__(256) void precompute_y(
    const float* __restrict__ x,
    const float* __restrict__ W1a, const float* __restrict__ b1a,
    const float* __restrict__ W2a, const float* __restrict__ b2a,
    float* __restrict__ y1, float* __restrict__ y2,
    int N, int ntiles)
{
    const int LDK = 136;                       // 128 + 8 pad
    __shared__ __align__(16) __bf16 w1t[64 * 136];
    __shared__ __align__(16) __bf16 w2t[64 * 136];
    for (int idx = threadIdx.x; idx < 64 * 128; idx += 256) {
        int k = idx >> 6, n = idx & 63;
        w1t[n * LDK + k] = (__bf16)W1a[k * 64 + n];
        w2t[n * LDK + k] = (__bf16)W2a[k * 64 + n];
    }
    __syncthreads();

    const int lane = threadIdx.x & 63, wave = threadIdx.x >> 6;
    const int l15 = lane & 15, l4 = lane >> 4;

    f32x4 bias1[4], bias2[4];
#pragma unroll
    for (int nt = 0; nt < 4; ++nt) {
        bias1[nt] = *(const f32x4*)(b1a + nt * 16 + l4 * 4);
        bias2[nt] = *(const f32x4*)(b2a + nt * 16 + l4 * 4);
    }

    for (int tile = blockIdx.x * 4 + wave; tile < ntiles; tile += gridDim.x * 4) {
        const int node = tile * 16 + l15;
        const int nrow = min(node, N - 1);
        f32x4 acc1[4], acc2[4];
#pragma unroll
        for (int nt = 0; nt < 4; ++nt) {
            acc1[nt] = (f32x4){0.f, 0.f, 0.f, 0.f};
            acc2[nt] = (f32x4){0.f, 0.f, 0.f, 0.f};
        }
#pragma unroll
        for (int j = 0; j < 4; ++j) {
            const int k0 = j * 32 + l4 * 8;
            bf16x8 b = cvt8(x + (size_t)nrow * 128 + k0);     // B = x^T (lane l15 = node)
#pragma unroll
            for (int nt = 0; nt < 4; ++nt) {
                bf16x8 a1 = *(const bf16x8*)(w1t + (nt * 16 + l15) * LDK + k0);  // A = W^T rows
                acc1[nt] = MFMA(a1, b, acc1[nt]);
                bf16x8 a2 = *(const bf16x8*)(w2t + (nt * 16 + l15) * LDK + k0);
                acc2[nt] = MFMA(a2, b, acc2[nt]);
            }
        }
        if (node < N) {
#pragma unroll
            for (int nt = 0; nt < 4; ++nt) {
                f32x4 v1 = acc1[nt] + bias1[nt];
                f32x4 v2 = acc2[nt] + bias2[nt];
                *(f32x4*)(y1 + (size_t)node * 64 + nt * 16 + l4 * 4) = v1;
                *(f32x4*)(y2 + (size_t)node * 64 + nt * 16 + l4 * 4) = v2;
            }
        }
    }
}

// ---------------------------------------------------------------------------
// Kernel 2 (transposed): per-edge  pre1 = y1[send] + eattr @ W1a[128:192,:]
//   msg = relu( relu(pre1) @ W1b + b1b );  agg[recv] += msg  (HW fp atomics)
// lane l15 owns edge (tile*16+l15); acc[nt][r] = out-col nt*16+l4*4+r.
// ---------------------------------------------------------------------------
__global__ __launch_bounds__(256) void edge_pass(
    const float* __restrict__ eattr,
    const int* __restrict__ send, const int* __restrict__ recv,
    const float* __restrict__ W1a, const float* __restrict__ W1b,
    const float* __restrict__ b1b,
    const float* __restrict__ y1, float* __restrict__ agg,
    int E, int ntiles)
{
    const int LDK = 72;                        // 64 + 8 pad
    __shared__ __align__(16) __bf16 wat[64 * 72];   // W1a[128:192,:]^T
    __shared__ __align__(16) __bf16 wbt[64 * 72];   // W1b^T
    __shared__ __align__(16) __bf16 hbuf[4][16 * 72];
    for (int idx = threadIdx.x; idx < 64 * 64; idx += 256) {
        int k = idx >> 6, n = idx & 63;
        wat[n * LDK + k] = (__bf16)W1a[(128 + k) * 64 + n];
        wbt[n * LDK + k] = (__bf16)W1b[k * 64 + n];
    }
    __syncthreads();

    const int lane = threadIdx.x & 63, wave = threadIdx.x >> 6;
    const int l15 = lane & 15, l4 = lane >> 4;
    __bf16* hb = hbuf[wave];

    f32x4 biasb[4];
#pragma unroll
    for (int nt = 0; nt < 4; ++nt) biasb[nt] = *(const f32x4*)(b1b + nt * 16 + l4 * 4);

    for (int tile = blockIdx.x * 4 + wave; tile < ntiles; tile += gridDim.x * 4) {
        const int e = tile * 16 + l15;
        const int eload = min(e, E - 1);
        const int s  = send[eload];
        const int rv = recv[eload];

        // ---- layer 1: C-init = y1[send] (vectorized gather), A = W1a_e^T, B = eattr^T
        f32x4 acc[4];
#pragma unroll
        for (int nt = 0; nt < 4; ++nt)
            acc[nt] = *(const f32x4*)(y1 + (size_t)s * 64 + nt * 16 + l4 * 4);
#pragma unroll
        for (int j = 0; j < 2; ++j) {
            const int k0 = j * 32 + l4 * 8;
            bf16x8 b = cvt8(eattr + (size_t)eload * 64 + k0);
#pragma unroll
            for (int nt = 0; nt < 4; ++nt) {
                bf16x8 a = *(const bf16x8*)(wat + (nt * 16 + l15) * LDK + k0);
                acc[nt] = MFMA(a, b, acc[nt]);
            }
        }
        // relu -> stage h tile: lane already holds 4 consecutive h-cols of its edge
#pragma unroll
        for (int nt = 0; nt < 4; ++nt) {
            bf16x4 hv;
#pragma unroll
            for (int r = 0; r < 4; ++r) hv[r] = (__bf16)fmaxf(acc[nt][r], 0.f);
            *(bf16x4*)(hb + l15 * LDK + nt * 16 + l4 * 4) = hv;
        }

        // ---- layer 2: A = W1b^T, B = h^T (LDS), C-init = b1b
        f32x4 acc2[4];
#pragma unroll
        for (int nt = 0; nt < 4; ++nt) acc2[nt] = biasb[nt];
#pragma unroll
        for (int j = 0; j < 2; ++j) {
            const int k0 = j * 32 + l4 * 8;
            bf16x8 b = *(const bf16x8*)(hb + l15 * LDK + k0);
#pragma unroll
            for (int nt = 0; nt < 4; ++nt) {
                bf16x8 a = *(const bf16x8*)(wbt + (nt * 16 + l15) * LDK + k0);
                acc2[nt] = MFMA(a, b, acc2[nt]);
            }
        }
        // relu + scatter-add: consecutive cols -> packed/HW atomics
        if (e < E) {
            float* base = agg + (size_t)rv * 64;
#pragma unroll
            for (int nt = 0; nt < 4; ++nt) {
                float v0 = fmaxf(acc2[nt][0], 0.f);
                float v1 = fmaxf(acc2[nt][1], 0.f);
                float v2 = fmaxf(acc2[nt][2], 0.f);
                float v3 = fmaxf(acc2[nt][3], 0.f);
                atom2(base + nt * 16 + l4 * 4, v0, v1);
                atom2(base + nt * 16 + l4 * 4 + 2, v2, v3);
            }
        }
    }
}

// ---------------------------------------------------------------------------
// Kernel 3 (transposed): per-node  pre = y2[n] + agg[n] @ W2a[128:192,:]
//   out = relu( relu(pre) @ W2b + b2b )
// ---------------------------------------------------------------------------
__global__ __launch_bounds__(256) void node_pass(
    const float* __restrict__ agg,
    const float* __restrict__ W2a, const float* __restrict__ W2b,
    const float* __restrict__ b2b,
    const float* __restrict__ y2, float* __restrict__ out,
    int N, int ntiles)
{
    const int LDK = 72;
    __shared__ __align__(16) __bf16 wat[64 * 72];   // W2a[128:192,:]^T
    __shared__ __align__(16) __bf16 wbt[64 * 72];   // W2b^T
    __shared__ __align__(16) __bf16 hbuf[4][16 * 72];
    for (int idx = threadIdx.x; idx < 64 * 64; idx += 256) {
        int k = idx >> 6, n = idx & 63;
        wat[n * LDK + k] = (__bf16)W2a[(128 + k) * 64 + n];
        wbt[n * LDK + k] = (__bf16)W2b[k * 64 + n];
    }
    __syncthreads();

    const int lane = threadIdx.x & 63, wave = threadIdx.x >> 6;
    const int l15 = lane & 15, l4 = lane >> 4;
    __bf16* hb = hbuf[wave];

    f32x4 biasb[4];
#pragma unroll
    for (int nt = 0; nt < 4; ++nt) biasb[nt] = *(const f32x4*)(b2b + nt * 16 + l4 * 4);

    for (int tile = blockIdx.x * 4 + wave; tile < ntiles; tile += gridDim.x * 4) {
        const int node = tile * 16 + l15;
        const int nrow = min(node, N - 1);

        f32x4 acc[4];
#pragma unroll
        for (int nt = 0; nt < 4; ++nt)
            acc[nt] = *(const f32x4*)(y2 + (size_t)nrow * 64 + nt * 16 + l4 * 4);
#pragma unroll
        for (int j = 0; j < 2; ++j) {
            const int k0 = j * 32 + l4 * 8;
            bf16x8 b = cvt8(agg + (size_t)nrow * 64 + k0);
#pragma unroll
            for (int nt = 0; nt < 4; ++nt) {
                bf16x8 a = *(const bf16x8*)(wat + (nt * 16 + l15) * LDK + k0);
                acc[nt] = MFMA(a, b, acc[nt]);
            }
        }
#pragma unroll
        for (int nt = 0; nt < 4; ++nt) {
            bf16x4 hv;
#pragma unroll
            for (int r = 0; r < 4; ++r) hv[r] = (__bf16)fmaxf(acc[nt][r], 0.f);
            *(bf16x4*)(hb + l15 * LDK + nt * 16 + l4 * 4) = hv;
        }

        f32x4 acc2[4];
#pragma unroll
        for (int nt = 0; nt < 4; ++nt) acc2[nt] = biasb[nt];
#pragma unroll
        for (int j = 0; j < 2; ++j) {
            const int k0 = j * 32 + l4 * 8;
            bf16x8 b = *(const bf16x8*)(hb + l15 * LDK + k0);
#pragma unroll
            for (int nt = 0; nt < 4; ++nt) {
                bf16x8 a = *(const bf16x8*)(wbt + (nt * 16 + l15) * LDK + k0);
                acc2[nt] = MFMA(a, b, acc2[nt]);
            }
        }
        if (node < N) {
#pragma unroll
            for (int nt = 0; nt < 4; ++nt) {
                f32x4 v;
#pragma unroll
                for (int r = 0; r < 4; ++r) v[r] = fmaxf(acc2[nt][r], 0.f);
                *(f32x4*)(out + (size_t)node * 64 + nt * 16 + l4 * 4) = v;
            }
        }
    }
}

// ---------------------------------------------------------------------------
extern "C" void kernel_launch(void* const* d_in, const int* in_sizes, int n_in,
                              void* d_out, int out_size, void* d_ws, size_t ws_size,
                              hipStream_t stream) {
    const float* x     = (const float*)d_in[0];
    const int*   eidx  = (const int*)d_in[1];
    const float* eattr = (const float*)d_in[2];
    // d_in[3] = u (unused), d_in[4] = batch (unused)
    const float* W1a = (const float*)d_in[5];
    const float* b1a = (const float*)d_in[6];
    const float* W1b = (const float*)d_in[7];
    const float* b1b = (const float*)d_in[8];
    const float* W2a = (const float*)d_in[9];
    const float* b2a = (const float*)d_in[10];
    const float* W2b = (const float*)d_in[11];
    const float* b2b = (const float*)d_in[12];
    float* out = (float*)d_out;

    const int N = in_sizes[0] / 128;
    const int E = in_sizes[1] / 2;
    const int* send = eidx;
    const int* recv = eidx + E;

    float* agg = (float*)d_ws;
    float* y1  = agg + (size_t)N * 64;
    float* y2  = y1 + (size_t)N * 64;

    hipMemsetAsync(agg, 0, (size_t)N * 64 * sizeof(float), stream);

    const int ntilesN = (N + 15) / 16;
    const int ntilesE = (E + 15) / 16;
    int blkN = (ntilesN + 3) / 4;
    if (blkN > 1024) blkN = 1024;
    int blkE = (ntilesE + 3) / 4;
    if (blkE > 1280) blkE = 1280;   // 5 blocks/CU LDS cap -> fully resident

    precompute_y<<<blkN, 256, 0, stream>>>(x, W1a, b1a, W2a, b2a, y1, y2, N, ntilesN);
    edge_pass<<<blkE, 256, 0, stream>>>(eattr, send, recv, W1a, W1b, b1b, y1, agg, E, ntilesE);
    node_pass<<<blkN, 256, 0, stream>>>(agg, W2a, W2b, b2b, y2, out, N, ntilesN);
}